// Round 13
// baseline (14.888 us; speedup 1.0000x reference)
//
#include <hip/hip_runtime.h>
#include <math.h>

#define PCNT 1024
#define HH 160
#define WW 160
#define NPIX (HH * WW)
#define TILE 8
#define TX (WW / TILE)       // 20
#define TY (HH / TILE)       // 20
#define NTILES (TX * TY)     // 400
#define NBLK 256             // 1 block/CU; block b owns tiles {b, b+256}

// Single dispatch. 512 threads = 8 waves. Phase A (preprocess all gaussians
// into LDS) runs once per block. Blocks 0-143 rasterize 2 tiles with two
// 4-wave groups concurrently; blocks 144-255 (one tile, includes the heavy
// image-center tiles) use all 8 waves on their single tile.
// Cull test is the EXACT ellipse-vs-tile test: min of the convex quadratic
// Q over the tile square vs tau (conservative slop) -- strictly tighter than
// the AABB of the ellipse.
__global__ __launch_bounds__(512) void k_all(
    const float* __restrict__ means, const float* __restrict__ cols,
    const float* __restrict__ ops, const float* __restrict__ scales,
    const float* __restrict__ rots, const float* __restrict__ vm,
    const float* __restrict__ pm, const float* __restrict__ bg,
    float* __restrict__ out)
{
    __shared__ float4 spA[PCNT];                 // 16 KB {px,py,alpha(ca'),beta(cb')}
    __shared__ float4 spB[PCNT];                 // 16 KB {gamma(cc'),op,cr,cg}
    __shared__ float  spC[PCNT];                 //  4 KB {cb}
    __shared__ float4 cl[PCNT];                  // 16 KB cull {px,py,tau2,-}
    __shared__ unsigned int kbits[PCNT];         //  4 KB depth key bits
    __shared__ __align__(16) unsigned long long sl[2][PCNT];   // 16 KB compacted keys
    __shared__ __align__(16) unsigned short ranked[2][PCNT];   //  4 KB ordered ids
    __shared__ float4 part[8][64];               //  8 KB wave partials (wave-indexed)
    __shared__ unsigned long long masks[2][16];
    __shared__ int offs[2][16];
    __shared__ int sn[2];

    int tid = threadIdx.x;
    int bid = blockIdx.x;
    int wave = tid >> 6, lane = tid & 63;

    // group geometry: 2 tiles -> 2 groups of 4 waves; 1 tile -> 1 group of 8
    bool two = (bid + NBLK) < NTILES;
    int gsz   = two ? 4 : 8;            // waves per group
    int group = two ? (wave >> 2) : 0;
    int gwave = two ? (wave & 3) : wave;
    int gtid  = tid - group * (gsz << 6);
    int cpw   = 16 / gsz;               // cull chunks per wave

    const float HL2E = 0.72134752044448170f;  // 0.5*log2(e)
    const float L2E  = 1.4426950408889634f;   // log2(e)

    // ---------------- Phase A: preprocess all gaussians into LDS (once) ----------------
    for (int i = tid; i < PCNT; i += 512) {
        float mx = means[3 * i], my = means[3 * i + 1], mz = means[3 * i + 2];

        float t0 = vm[0] * mx + vm[1] * my + vm[2] * mz + vm[3];
        float t1 = vm[4] * mx + vm[5] * my + vm[6] * mz + vm[7];
        float t2 = vm[8] * mx + vm[9] * my + vm[10] * mz + vm[11];
        bool depth_ok = t2 > 0.2f;

        float ph0 = pm[0] * mx + pm[1] * my + pm[2] * mz + pm[3];
        float ph1 = pm[4] * mx + pm[5] * my + pm[6] * mz + pm[7];
        float ph3 = pm[12] * mx + pm[13] * my + pm[14] * mz + pm[15];
        float pw = 1.0f / (ph3 + 1e-7f);
        float px = ((ph0 * pw + 1.0f) * (float)WW - 1.0f) * 0.5f;
        float py = ((ph1 * pw + 1.0f) * (float)HH - 1.0f) * 0.5f;

        float4 q = *(const float4*)(rots + 4 * i);
        float qr = q.x, qx = q.y, qy = q.z, qz = q.w;
        float R00 = 1.f - 2.f * (qy * qy + qz * qz), R01 = 2.f * (qx * qy - qr * qz), R02 = 2.f * (qx * qz + qr * qy);
        float R10 = 2.f * (qx * qy + qr * qz), R11 = 1.f - 2.f * (qx * qx + qz * qz), R12 = 2.f * (qy * qz - qr * qx);
        float R20 = 2.f * (qx * qz - qr * qy), R21 = 2.f * (qy * qz + qr * qx), R22 = 1.f - 2.f * (qx * qx + qy * qy);

        float s0 = scales[3 * i], s1 = scales[3 * i + 1], s2 = scales[3 * i + 2];
        float M00 = R00 * s0, M01 = R01 * s1, M02 = R02 * s2;
        float M10 = R10 * s0, M11 = R11 * s1, M12 = R12 * s2;
        float M20 = R20 * s0, M21 = R21 * s1, M22 = R22 * s2;
        float c00 = M00 * M00 + M01 * M01 + M02 * M02;
        float c01 = M00 * M10 + M01 * M11 + M02 * M12;
        float c02 = M00 * M20 + M01 * M21 + M02 * M22;
        float c11 = M10 * M10 + M11 * M11 + M12 * M12;
        float c12 = M10 * M20 + M11 * M21 + M12 * M22;
        float c22 = M20 * M20 + M21 * M21 + M22 * M22;

        const float fx = 160.0f, fy = 160.0f;
        const float limx = 0.65f, limy = 0.65f;
        float txz = fminf(limx, fmaxf(-limx, t0 / t2)) * t2;
        float tyz = fminf(limy, fmaxf(-limy, t1 / t2)) * t2;
        float rz = 1.0f / t2;
        float J00 = fx * rz, J02 = -fx * txz * rz * rz;
        float J11 = fy * rz, J12 = -fy * tyz * rz * rz;

        float T00 = J00 * vm[0] + J02 * vm[8];
        float T01 = J00 * vm[1] + J02 * vm[9];
        float T02 = J00 * vm[2] + J02 * vm[10];
        float T10 = J11 * vm[4] + J12 * vm[8];
        float T11 = J11 * vm[5] + J12 * vm[9];
        float T12 = J11 * vm[6] + J12 * vm[10];

        float u00 = T00 * c00 + T01 * c01 + T02 * c02;
        float u01 = T00 * c01 + T01 * c11 + T02 * c12;
        float u02 = T00 * c02 + T01 * c12 + T02 * c22;
        float u10 = T10 * c00 + T11 * c01 + T12 * c02;
        float u11 = T10 * c01 + T11 * c11 + T12 * c12;
        float u12 = T10 * c02 + T11 * c12 + T12 * c22;
        float a  = u00 * T00 + u01 * T01 + u02 * T02 + 0.3f;
        float bb = u00 * T10 + u01 * T11 + u02 * T12;
        float cc = u10 * T10 + u11 * T11 + u12 * T12 + 0.3f;

        float det = a * cc - bb * bb;
        bool det_ok = det > 0.0f;
        float inv_det = det_ok ? 1.0f / det : 0.0f;
        float conA = cc * inv_det, conB = -bb * inv_det, conC = a * inv_det;
        float mid = 0.5f * (a + cc);
        float lam1 = mid + sqrtf(fmaxf(0.1f, mid * mid - det));
        float radius = ceilf(3.0f * sqrtf(lam1));
        bool valid = depth_ok && det_ok;

        if (bid == 0)
            out[3 * NPIX + i] = valid ? (float)(int)radius : 0.0f;

        if (valid) {
            float op = ops[i];
            // contribution exactly 0 unless Q2 <= tau2 (alpha >= 1/255) in
            // log2 domain: Q2 = ca'*dx^2 + cb'*dx*dy + cc'*dy^2,
            // tau2 = log2(255*op); +0.05 slop absorbs v_log/fp error.
            float l2; asm("v_log_f32 %0, %1" : "=v"(l2) : "v"(255.0f * op));
            float tau2 = fmaxf(l2 + 0.05f, 0.0f);
            spA[i] = make_float4(px, py, conA * HL2E, conB * L2E);
            spB[i] = make_float4(conC * HL2E, op, cols[3 * i], cols[3 * i + 1]);
            spC[i] = cols[3 * i + 2];
            cl[i] = make_float4(px, py, tau2, 0.f);
            kbits[i] = __float_as_uint(t2);
        } else {
            spA[i] = make_float4(0.f, 0.f, 0.f, 0.f);
            spB[i] = make_float4(0.f, 0.f, 0.f, 0.f);
            spC[i] = 0.f;
            cl[i] = make_float4(0.f, 0.f, -1e30f, 0.f);  // tau2=-inf: never kept
            kbits[i] = 0x7f800000u;
        }
    }
    __syncthreads();

    // ---------------- Per-group tile rasterization ----------------
    int tile = bid + group * NBLK;
    int tx = tile % TX, ty = tile / TX;
    float x0 = (float)(tx * TILE), y0 = (float)(ty * TILE);

    // Phase B: exact ellipse-vs-tile cull + ordered compaction. Pixels are
    // integers in [x0,x0+7]x[y0,y0+7]. min over the square of the convex
    // quadratic Q2: 0 if center inside, else min over the 4 edges (clamped
    // 1D quadratic minima). Keep iff min <= tau2.
    for (int k = 0; k < cpw; ++k) {
        int c = gwave * cpw + k;
        int g = c * 64 + lane;
        float4 cv = cl[g];            // px,py,tau2
        float alf = spA[g].z;         // ca'
        float bet = spA[g].w;         // cb'
        float gam = spB[g].x;         // cc'
        float dxl = x0 - cv.x, dxh = x0 + 7.0f - cv.x;
        float dyl = y0 - cv.y, dyh = y0 + 7.0f - cv.y;

        // x-edges (dx fixed): dy* = -bet*dx/(2 gam), clamped
        float t0e = fminf(fmaxf(-bet * dxl / (2.0f * gam), dyl), dyh);
        float q0 = alf * dxl * dxl + bet * dxl * t0e + gam * t0e * t0e;
        float t1e = fminf(fmaxf(-bet * dxh / (2.0f * gam), dyl), dyh);
        float q1 = alf * dxh * dxh + bet * dxh * t1e + gam * t1e * t1e;
        // y-edges (dy fixed): dx* = -bet*dy/(2 alf), clamped
        float t2e = fminf(fmaxf(-bet * dyl / (2.0f * alf), dxl), dxh);
        float q2 = alf * t2e * t2e + bet * t2e * dyl + gam * dyl * dyl;
        float t3e = fminf(fmaxf(-bet * dyh / (2.0f * alf), dxl), dxh);
        float q3 = alf * t3e * t3e + bet * t3e * dyh + gam * dyh * dyh;

        bool inside = (dxl <= 0.0f) & (dxh >= 0.0f) & (dyl <= 0.0f) & (dyh >= 0.0f);
        float m = fminf(fminf(q0, q1), fminf(q2, q3));
        if (inside) m = 0.0f;
        bool ov = (m <= cv.z);

        unsigned long long mk = __ballot(ov);
        if (lane == 0) masks[group][c] = mk;
    }
    __syncthreads();
    if (gtid == 0) {
        int acc = 0;
        #pragma unroll
        for (int c = 0; c < 16; ++c) { offs[group][c] = acc; acc += __popcll(masks[group][c]); }
        sn[group] = acc;
    }
    __syncthreads();
    for (int k = 0; k < cpw; ++k) {
        int c = gwave * cpw + k;
        unsigned long long m = masks[group][c];
        if ((m >> lane) & 1ull) {
            int g = c * 64 + lane;
            int pos = offs[group][c] + __popcll(m & ((1ull << lane) - 1ull));
            sl[group][pos] = ((unsigned long long)kbits[g] << 32) | (unsigned int)g;
        }
    }
    __syncthreads();
    int n = sn[group];
    // pad to multiple of 4 with max-keys so rank scans can read pairs
    for (int t = n + gtid; t < ((n + 3) & ~3) && t < PCNT; t += 64 * gsz)
        sl[group][t] = ~0ull;
    __syncthreads();

    // Phase C: rank-by-count ordering (keys unique; broadcast b128 scans)
    for (int t = gtid; t < n; t += 64 * gsz) {
        unsigned long long key = sl[group][t];
        int cnt = 0;
        const unsigned long long* base = sl[group];
        for (int k = 0; k < n; k += 4) {
            ulonglong2 p0 = *(const ulonglong2*)(base + k);
            ulonglong2 p1 = *(const ulonglong2*)(base + k + 2);
            cnt += (p0.x < key) ? 1 : 0;
            cnt += (p0.y < key) ? 1 : 0;
            cnt += (p1.x < key) ? 1 : 0;
            cnt += (p1.y < key) ? 1 : 0;
        }
        ranked[group][cnt] = (unsigned short)(key & 1023u);
    }
    __syncthreads();

    // Phase D: segmented front-to-back composite, 4x software-pipelined.
    // Segment starts aligned to 4 so ids load as one ushort4 (b64).
    float fxp = x0 + (float)(lane & 7);
    float fyp = y0 + (float)(lane >> 3);

    float T = 1.0f, C0 = 0.f, C1 = 0.f, C2 = 0.f;
    int per = (n + gsz - 1) / gsz;
    per = (per + 3) & ~3;
    int lo = gwave * per; if (lo > n) lo = n;
    int hi = min(n, lo + per);
    int i = lo;
    for (; i + 4 <= hi; i += 4) {
        ushort4 ids = *(const ushort4*)(&ranked[group][i]);
        int id0 = ids.x, id1 = ids.y, id2 = ids.z, id3 = ids.w;
        float4 A0 = spA[id0], B0 = spB[id0];
        float4 A1 = spA[id1], B1 = spB[id1];
        float4 A2 = spA[id2], B2 = spB[id2];
        float4 A3 = spA[id3], B3 = spB[id3];
        float cb0 = spC[id0], cb1 = spC[id1], cb2 = spC[id2], cb3 = spC[id3];

        float dx0 = A0.x - fxp, dy0 = A0.y - fyp;
        float dx1 = A1.x - fxp, dy1 = A1.y - fyp;
        float dx2 = A2.x - fxp, dy2 = A2.y - fyp;
        float dx3 = A3.x - fxp, dy3 = A3.y - fyp;
        float p0 = -(A0.z * dx0 * dx0 + B0.x * dy0 * dy0) - A0.w * dx0 * dy0;
        float p1 = -(A1.z * dx1 * dx1 + B1.x * dy1 * dy1) - A1.w * dx1 * dy1;
        float p2 = -(A2.z * dx2 * dx2 + B2.x * dy2 * dy2) - A2.w * dx2 * dy2;
        float p3 = -(A3.z * dx3 * dx3 + B3.x * dy3 * dy3) - A3.w * dx3 * dy3;
        float e0, e1, e2, e3;
        asm("v_exp_f32 %0, %1" : "=v"(e0) : "v"(p0));
        asm("v_exp_f32 %0, %1" : "=v"(e1) : "v"(p1));
        asm("v_exp_f32 %0, %1" : "=v"(e2) : "v"(p2));
        asm("v_exp_f32 %0, %1" : "=v"(e3) : "v"(p3));
        float al0 = fminf(0.99f, B0.y * e0); if (p0 > 0.0f || al0 < (1.0f / 255.0f)) al0 = 0.0f;
        float al1 = fminf(0.99f, B1.y * e1); if (p1 > 0.0f || al1 < (1.0f / 255.0f)) al1 = 0.0f;
        float al2 = fminf(0.99f, B2.y * e2); if (p2 > 0.0f || al2 < (1.0f / 255.0f)) al2 = 0.0f;
        float al3 = fminf(0.99f, B3.y * e3); if (p3 > 0.0f || al3 < (1.0f / 255.0f)) al3 = 0.0f;

        float w;
        w = al0 * T; C0 = fmaf(w, B0.z, C0); C1 = fmaf(w, B0.w, C1); C2 = fmaf(w, cb0, C2); T *= (1.0f - al0);
        w = al1 * T; C0 = fmaf(w, B1.z, C0); C1 = fmaf(w, B1.w, C1); C2 = fmaf(w, cb1, C2); T *= (1.0f - al1);
        w = al2 * T; C0 = fmaf(w, B2.z, C0); C1 = fmaf(w, B2.w, C1); C2 = fmaf(w, cb2, C2); T *= (1.0f - al2);
        w = al3 * T; C0 = fmaf(w, B3.z, C0); C1 = fmaf(w, B3.w, C1); C2 = fmaf(w, cb3, C2); T *= (1.0f - al3);
    }
    for (; i < hi; ++i) {
        int id = ranked[group][i];
        float4 v0 = spA[id];
        float4 v1 = spB[id];
        float cbv = spC[id];
        float dx = v0.x - fxp, dy = v0.y - fyp;
        float p = -(v0.z * dx * dx + v1.x * dy * dy) - v0.w * dx * dy;
        float e; asm("v_exp_f32 %0, %1" : "=v"(e) : "v"(p));
        float al = fminf(0.99f, v1.y * e);
        if (p > 0.0f || al < (1.0f / 255.0f)) al = 0.0f;
        float w = al * T;
        C0 = fmaf(w, v1.z, C0);
        C1 = fmaf(w, v1.w, C1);
        C2 = fmaf(w, cbv, C2);
        T *= (1.0f - al);
    }

    part[wave][lane] = make_float4(C0, C1, C2, T);
    __syncthreads();

    if (gtid < 64) {
        float Tt = 1.0f, c0 = 0.f, c1 = 0.f, c2 = 0.f;
        int sbase = group * gsz;
        for (int s = 0; s < gsz; ++s) {
            float4 v = part[sbase + s][gtid];
            c0 = fmaf(Tt, v.x, c0);
            c1 = fmaf(Tt, v.y, c1);
            c2 = fmaf(Tt, v.z, c2);
            Tt *= v.w;
        }
        int pix = (ty * TILE + (gtid >> 3)) * WW + tx * TILE + (gtid & 7);
        out[pix]            = c0 + Tt * bg[0];
        out[NPIX + pix]     = c1 + Tt * bg[1];
        out[2 * NPIX + pix] = c2 + Tt * bg[2];
    }
}

extern "C" void kernel_launch(void* const* d_in, const int* in_sizes, int n_in,
                              void* d_out, int out_size, void* d_ws, size_t ws_size,
                              hipStream_t stream) {
    const float* means  = (const float*)d_in[0];
    const float* cols   = (const float*)d_in[2];
    const float* ops    = (const float*)d_in[3];
    const float* scales = (const float*)d_in[4];
    const float* rots   = (const float*)d_in[5];
    const float* bg     = (const float*)d_in[6];
    const float* vm     = (const float*)d_in[7];
    const float* pm     = (const float*)d_in[8];

    float* out = (float*)d_out;   // [3*NPIX color][PCNT radii-as-float]

    k_all<<<NBLK, 512, 0, stream>>>(means, cols, ops, scales, rots, vm, pm, bg, out);
}

// Round 14
// 14.278 us; speedup vs baseline: 1.0427x; 1.0427x over previous
//
#include <hip/hip_runtime.h>
#include <math.h>

#define PCNT 1024
#define HH 160
#define WW 160
#define NPIX (HH * WW)
#define TILE 8
#define TX (WW / TILE)       // 20
#define TY (HH / TILE)       // 20
#define NTILES (TX * TY)     // 400
#define NBLK 256             // 1 block/CU; block b owns tiles {b, b+256}

// Single dispatch. 512 threads = 8 waves. Phase A (preprocess all gaussians
// into LDS) runs once per block. Blocks 0-143 rasterize 2 tiles with two
// 4-wave groups concurrently; blocks 144-255 (one tile, includes the heavy
// image-center tiles) use all 8 waves on their single tile.
__global__ __launch_bounds__(512) void k_all(
    const float* __restrict__ means, const float* __restrict__ cols,
    const float* __restrict__ ops, const float* __restrict__ scales,
    const float* __restrict__ rots, const float* __restrict__ vm,
    const float* __restrict__ pm, const float* __restrict__ bg,
    float* __restrict__ out)
{
    __shared__ float4 spA[PCNT];                 // 16 KB {px,py,ca',cb'}
    __shared__ float4 spB[PCNT];                 // 16 KB {cc',op,cr,cg}
    __shared__ float  spC[PCNT];                 //  4 KB {cb}
    __shared__ float4 cl[PCNT];                  // 16 KB cull {px,py,hx,hy}
    __shared__ unsigned int kbits[PCNT];         //  4 KB depth key bits
    __shared__ __align__(16) unsigned long long sl[2][PCNT];   // 16 KB compacted keys
    __shared__ __align__(16) unsigned short ranked[2][PCNT];   //  4 KB ordered ids
    __shared__ float4 part[8][64];               //  8 KB wave partials (wave-indexed)
    __shared__ unsigned long long masks[2][16];
    __shared__ int offs[2][16];
    __shared__ int sn[2];

    int tid = threadIdx.x;
    int bid = blockIdx.x;
    int wave = tid >> 6, lane = tid & 63;

    // group geometry: 2 tiles -> 2 groups of 4 waves; 1 tile -> 1 group of 8
    bool two = (bid + NBLK) < NTILES;
    int gsz   = two ? 4 : 8;            // waves per group
    int group = two ? (wave >> 2) : 0;
    int gwave = two ? (wave & 3) : wave;
    int gtid  = tid - group * (gsz << 6);
    int cpw   = 16 / gsz;               // cull chunks per wave

    const float HL2E = 0.72134752044448170f;  // 0.5*log2(e)
    const float L2E  = 1.4426950408889634f;   // log2(e)
    const float LN2  = 0.69314718055994531f;

    // ---------------- Phase A: preprocess all gaussians into LDS (once) ----------------
    for (int i = tid; i < PCNT; i += 512) {
        float mx = means[3 * i], my = means[3 * i + 1], mz = means[3 * i + 2];

        float t0 = vm[0] * mx + vm[1] * my + vm[2] * mz + vm[3];
        float t1 = vm[4] * mx + vm[5] * my + vm[6] * mz + vm[7];
        float t2 = vm[8] * mx + vm[9] * my + vm[10] * mz + vm[11];
        bool depth_ok = t2 > 0.2f;

        float ph0 = pm[0] * mx + pm[1] * my + pm[2] * mz + pm[3];
        float ph1 = pm[4] * mx + pm[5] * my + pm[6] * mz + pm[7];
        float ph3 = pm[12] * mx + pm[13] * my + pm[14] * mz + pm[15];
        float pw = 1.0f / (ph3 + 1e-7f);
        float px = ((ph0 * pw + 1.0f) * (float)WW - 1.0f) * 0.5f;
        float py = ((ph1 * pw + 1.0f) * (float)HH - 1.0f) * 0.5f;

        float4 q = *(const float4*)(rots + 4 * i);
        float qr = q.x, qx = q.y, qy = q.z, qz = q.w;
        float R00 = 1.f - 2.f * (qy * qy + qz * qz), R01 = 2.f * (qx * qy - qr * qz), R02 = 2.f * (qx * qz + qr * qy);
        float R10 = 2.f * (qx * qy + qr * qz), R11 = 1.f - 2.f * (qx * qx + qz * qz), R12 = 2.f * (qy * qz - qr * qx);
        float R20 = 2.f * (qx * qz - qr * qy), R21 = 2.f * (qy * qz + qr * qx), R22 = 1.f - 2.f * (qx * qx + qy * qy);

        float s0 = scales[3 * i], s1 = scales[3 * i + 1], s2 = scales[3 * i + 2];
        float M00 = R00 * s0, M01 = R01 * s1, M02 = R02 * s2;
        float M10 = R10 * s0, M11 = R11 * s1, M12 = R12 * s2;
        float M20 = R20 * s0, M21 = R21 * s1, M22 = R22 * s2;
        float c00 = M00 * M00 + M01 * M01 + M02 * M02;
        float c01 = M00 * M10 + M01 * M11 + M02 * M12;
        float c02 = M00 * M20 + M01 * M21 + M02 * M22;
        float c11 = M10 * M10 + M11 * M11 + M12 * M12;
        float c12 = M10 * M20 + M11 * M21 + M12 * M22;
        float c22 = M20 * M20 + M21 * M21 + M22 * M22;

        const float fx = 160.0f, fy = 160.0f;
        const float limx = 0.65f, limy = 0.65f;
        float txz = fminf(limx, fmaxf(-limx, t0 / t2)) * t2;
        float tyz = fminf(limy, fmaxf(-limy, t1 / t2)) * t2;
        float rz = 1.0f / t2;
        float J00 = fx * rz, J02 = -fx * txz * rz * rz;
        float J11 = fy * rz, J12 = -fy * tyz * rz * rz;

        float T00 = J00 * vm[0] + J02 * vm[8];
        float T01 = J00 * vm[1] + J02 * vm[9];
        float T02 = J00 * vm[2] + J02 * vm[10];
        float T10 = J11 * vm[4] + J12 * vm[8];
        float T11 = J11 * vm[5] + J12 * vm[9];
        float T12 = J11 * vm[6] + J12 * vm[10];

        float u00 = T00 * c00 + T01 * c01 + T02 * c02;
        float u01 = T00 * c01 + T01 * c11 + T02 * c12;
        float u02 = T00 * c02 + T01 * c12 + T02 * c22;
        float u10 = T10 * c00 + T11 * c01 + T12 * c02;
        float u11 = T10 * c01 + T11 * c11 + T12 * c12;
        float u12 = T10 * c02 + T11 * c12 + T12 * c22;
        float a  = u00 * T00 + u01 * T01 + u02 * T02 + 0.3f;
        float bb = u00 * T10 + u01 * T11 + u02 * T12;
        float cc = u10 * T10 + u11 * T11 + u12 * T12 + 0.3f;

        float det = a * cc - bb * bb;
        bool det_ok = det > 0.0f;
        float inv_det = det_ok ? 1.0f / det : 0.0f;
        float conA = cc * inv_det, conB = -bb * inv_det, conC = a * inv_det;
        float mid = 0.5f * (a + cc);
        float lam1 = mid + sqrtf(fmaxf(0.1f, mid * mid - det));
        float radius = ceilf(3.0f * sqrtf(lam1));
        bool valid = depth_ok && det_ok;

        if (bid == 0)
            out[3 * NPIX + i] = valid ? (float)(int)radius : 0.0f;

        if (valid) {
            float op = ops[i];
            // contribution exactly 0 unless Q <= tau (alpha >= 1/255);
            // exact marginal projection of {Q<=tau}: |dx|<=hx=sqrt(2*tau*a),
            // |dy|<=hy=sqrt(2*tau*c); +0.02 slop absorbs v_log/fp error.
            float l2; asm("v_log_f32 %0, %1" : "=v"(l2) : "v"(255.0f * op));
            float tau = fmaxf(fmaf(l2, LN2, 0.02f), 0.0f);
            float hx = sqrtf(2.0f * tau * a);
            float hy = sqrtf(2.0f * tau * cc);
            spA[i] = make_float4(px, py, conA * HL2E, conB * L2E);
            spB[i] = make_float4(conC * HL2E, op, cols[3 * i], cols[3 * i + 1]);
            spC[i] = cols[3 * i + 2];
            cl[i] = make_float4(px, py, hx, hy);
            kbits[i] = __float_as_uint(t2);
        } else {
            spA[i] = make_float4(0.f, 0.f, 0.f, 0.f);
            spB[i] = make_float4(0.f, 0.f, 0.f, 0.f);
            spC[i] = 0.f;
            cl[i] = make_float4(0.f, 0.f, -1e9f, -1e9f);  // never overlaps
            kbits[i] = 0x7f800000u;
        }
    }
    __syncthreads();

    // ---------------- Per-group tile rasterization ----------------
    int tile = bid + group * NBLK;
    int tx = tile % TX, ty = tile / TX;
    float x0 = (float)(tx * TILE), y0 = (float)(ty * TILE);

    // Phase B: cull + ordered compaction. Pixels are integers in
    // [x0, x0+7] x [y0, y0+7], so exact conservative test vs +-h box:
    for (int k = 0; k < cpw; ++k) {
        int c = gwave * cpw + k;
        float4 cv = cl[c * 64 + lane];
        bool ov = (cv.x + cv.z >= x0) & (cv.x - cv.z <= x0 + (float)(TILE - 1)) &
                  (cv.y + cv.w >= y0) & (cv.y - cv.w <= y0 + (float)(TILE - 1));
        unsigned long long m = __ballot(ov);
        if (lane == 0) masks[group][c] = m;
    }
    __syncthreads();
    if (gtid == 0) {
        int acc = 0;
        #pragma unroll
        for (int c = 0; c < 16; ++c) { offs[group][c] = acc; acc += __popcll(masks[group][c]); }
        sn[group] = acc;
    }
    __syncthreads();
    for (int k = 0; k < cpw; ++k) {
        int c = gwave * cpw + k;
        unsigned long long m = masks[group][c];
        if ((m >> lane) & 1ull) {
            int g = c * 64 + lane;
            int pos = offs[group][c] + __popcll(m & ((1ull << lane) - 1ull));
            sl[group][pos] = ((unsigned long long)kbits[g] << 32) | (unsigned int)g;
        }
    }
    __syncthreads();
    int n = sn[group];
    // pad to multiple of 4 with max-keys so rank scans can read pairs
    for (int t = n + gtid; t < ((n + 3) & ~3) && t < PCNT; t += 64 * gsz)
        sl[group][t] = ~0ull;
    __syncthreads();

    // Phase C: rank-by-count ordering (keys unique; broadcast b128 scans)
    for (int t = gtid; t < n; t += 64 * gsz) {
        unsigned long long key = sl[group][t];
        int cnt = 0;
        const unsigned long long* base = sl[group];
        for (int k = 0; k < n; k += 4) {
            ulonglong2 p0 = *(const ulonglong2*)(base + k);
            ulonglong2 p1 = *(const ulonglong2*)(base + k + 2);
            cnt += (p0.x < key) ? 1 : 0;
            cnt += (p0.y < key) ? 1 : 0;
            cnt += (p1.x < key) ? 1 : 0;
            cnt += (p1.y < key) ? 1 : 0;
        }
        ranked[group][cnt] = (unsigned short)(key & 1023u);
    }
    __syncthreads();

    // Phase D: segmented front-to-back composite, 4x software-pipelined.
    // Segment starts aligned to 4 so ids load as one ushort4 (b64).
    float fxp = x0 + (float)(lane & 7);
    float fyp = y0 + (float)(lane >> 3);

    float T = 1.0f, C0 = 0.f, C1 = 0.f, C2 = 0.f;
    int per = (n + gsz - 1) / gsz;
    per = (per + 3) & ~3;
    int lo = gwave * per; if (lo > n) lo = n;
    int hi = min(n, lo + per);
    int i = lo;
    for (; i + 4 <= hi; i += 4) {
        ushort4 ids = *(const ushort4*)(&ranked[group][i]);
        int id0 = ids.x, id1 = ids.y, id2 = ids.z, id3 = ids.w;
        float4 A0 = spA[id0], B0 = spB[id0];
        float4 A1 = spA[id1], B1 = spB[id1];
        float4 A2 = spA[id2], B2 = spB[id2];
        float4 A3 = spA[id3], B3 = spB[id3];
        float cb0 = spC[id0], cb1 = spC[id1], cb2 = spC[id2], cb3 = spC[id3];

        float dx0 = A0.x - fxp, dy0 = A0.y - fyp;
        float dx1 = A1.x - fxp, dy1 = A1.y - fyp;
        float dx2 = A2.x - fxp, dy2 = A2.y - fyp;
        float dx3 = A3.x - fxp, dy3 = A3.y - fyp;
        float p0 = -(A0.z * dx0 * dx0 + B0.x * dy0 * dy0) - A0.w * dx0 * dy0;
        float p1 = -(A1.z * dx1 * dx1 + B1.x * dy1 * dy1) - A1.w * dx1 * dy1;
        float p2 = -(A2.z * dx2 * dx2 + B2.x * dy2 * dy2) - A2.w * dx2 * dy2;
        float p3 = -(A3.z * dx3 * dx3 + B3.x * dy3 * dy3) - A3.w * dx3 * dy3;
        float e0, e1, e2, e3;
        asm("v_exp_f32 %0, %1" : "=v"(e0) : "v"(p0));
        asm("v_exp_f32 %0, %1" : "=v"(e1) : "v"(p1));
        asm("v_exp_f32 %0, %1" : "=v"(e2) : "v"(p2));
        asm("v_exp_f32 %0, %1" : "=v"(e3) : "v"(p3));
        float al0 = fminf(0.99f, B0.y * e0); if (p0 > 0.0f || al0 < (1.0f / 255.0f)) al0 = 0.0f;
        float al1 = fminf(0.99f, B1.y * e1); if (p1 > 0.0f || al1 < (1.0f / 255.0f)) al1 = 0.0f;
        float al2 = fminf(0.99f, B2.y * e2); if (p2 > 0.0f || al2 < (1.0f / 255.0f)) al2 = 0.0f;
        float al3 = fminf(0.99f, B3.y * e3); if (p3 > 0.0f || al3 < (1.0f / 255.0f)) al3 = 0.0f;

        float w;
        w = al0 * T; C0 = fmaf(w, B0.z, C0); C1 = fmaf(w, B0.w, C1); C2 = fmaf(w, cb0, C2); T *= (1.0f - al0);
        w = al1 * T; C0 = fmaf(w, B1.z, C0); C1 = fmaf(w, B1.w, C1); C2 = fmaf(w, cb1, C2); T *= (1.0f - al1);
        w = al2 * T; C0 = fmaf(w, B2.z, C0); C1 = fmaf(w, B2.w, C1); C2 = fmaf(w, cb2, C2); T *= (1.0f - al2);
        w = al3 * T; C0 = fmaf(w, B3.z, C0); C1 = fmaf(w, B3.w, C1); C2 = fmaf(w, cb3, C2); T *= (1.0f - al3);
    }
    for (; i < hi; ++i) {
        int id = ranked[group][i];
        float4 v0 = spA[id];
        float4 v1 = spB[id];
        float cbv = spC[id];
        float dx = v0.x - fxp, dy = v0.y - fyp;
        float p = -(v0.z * dx * dx + v1.x * dy * dy) - v0.w * dx * dy;
        float e; asm("v_exp_f32 %0, %1" : "=v"(e) : "v"(p));
        float al = fminf(0.99f, v1.y * e);
        if (p > 0.0f || al < (1.0f / 255.0f)) al = 0.0f;
        float w = al * T;
        C0 = fmaf(w, v1.z, C0);
        C1 = fmaf(w, v1.w, C1);
        C2 = fmaf(w, cbv, C2);
        T *= (1.0f - al);
    }

    part[wave][lane] = make_float4(C0, C1, C2, T);
    __syncthreads();

    if (gtid < 64) {
        float Tt = 1.0f, c0 = 0.f, c1 = 0.f, c2 = 0.f;
        int sbase = group * gsz;
        for (int s = 0; s < gsz; ++s) {
            float4 v = part[sbase + s][gtid];
            c0 = fmaf(Tt, v.x, c0);
            c1 = fmaf(Tt, v.y, c1);
            c2 = fmaf(Tt, v.z, c2);
            Tt *= v.w;
        }
        int pix = (ty * TILE + (gtid >> 3)) * WW + tx * TILE + (gtid & 7);
        out[pix]            = c0 + Tt * bg[0];
        out[NPIX + pix]     = c1 + Tt * bg[1];
        out[2 * NPIX + pix] = c2 + Tt * bg[2];
    }
}

extern "C" void kernel_launch(void* const* d_in, const int* in_sizes, int n_in,
                              void* d_out, int out_size, void* d_ws, size_t ws_size,
                              hipStream_t stream) {
    const float* means  = (const float*)d_in[0];
    const float* cols   = (const float*)d_in[2];
    const float* ops    = (const float*)d_in[3];
    const float* scales = (const float*)d_in[4];
    const float* rots   = (const float*)d_in[5];
    const float* bg     = (const float*)d_in[6];
    const float* vm     = (const float*)d_in[7];
    const float* pm     = (const float*)d_in[8];

    float* out = (float*)d_out;   // [3*NPIX color][PCNT radii-as-float]

    k_all<<<NBLK, 512, 0, stream>>>(means, cols, ops, scales, rots, vm, pm, bg, out);
}